// Round 7
// baseline (3166.689 us; speedup 1.0000x reference)
//
#include <hip/hip_runtime.h>
#include <hip/hip_bf16.h>
#include <cstdint>
#include <cstddef>

#define S_LEN 2048
#define NH 12
#define HD 64
#define EDIM 768
// exponent = -(D_INTRINSIC + BETA) = -3.5, BANDWIDTH^0.5 = 1

typedef short bf16x8 __attribute__((ext_vector_type(8)));
typedef float f32x4  __attribute__((ext_vector_type(4)));

__device__ __forceinline__ unsigned short f2bf(float f) {
    return __bfloat16_as_ushort(__float2bfloat16(f));
}
__device__ __forceinline__ float bf2f(unsigned short u) {
    union { unsigned int i; float f; } x;
    x.i = ((unsigned int)u) << 16;
    return x.f;
}
__device__ __forceinline__ float rsq_f32(float x) {
#if __has_builtin(__builtin_amdgcn_rsqf)
    return __builtin_amdgcn_rsqf(x);
#else
    return __builtin_amdgcn_rcpf(__builtin_amdgcn_sqrtf(x));
#endif
}

// ---------------------------------------------------------------------------
// Kernel 0: one-shot fp32 -> bf16 pre-cast of hs, Wq|Wv (concatenated), Wo.
// ---------------------------------------------------------------------------
__global__ __launch_bounds__(256) void precast_kernel(
    const float* __restrict__ hs, const float* __restrict__ Wq,
    const float* __restrict__ Wv, const float* __restrict__ Wo,
    unsigned short* __restrict__ hsb, unsigned short* __restrict__ Wqvb,
    unsigned short* __restrict__ Wob)
{
    const int i4 = blockIdx.x * 256 + threadIdx.x;   // 0..1228799
    const float* src;
    unsigned short* dst;
    int rel;
    if (i4 < 786432)        { src = hs; dst = hsb;            rel = i4; }
    else if (i4 < 933888)   { src = Wq; dst = Wqvb;           rel = i4 - 786432; }
    else if (i4 < 1081344)  { src = Wv; dst = Wqvb + 589824;  rel = i4 - 933888; }
    else                    { src = Wo; dst = Wob;            rel = i4 - 1081344; }
    float4 v = ((const float4*)src)[rel];
    ushort4 o;
    o.x = f2bf(v.x); o.y = f2bf(v.y); o.z = f2bf(v.z); o.w = f2bf(v.w);
    ((ushort4*)dst)[rel] = o;
}

// ---------------------------------------------------------------------------
// Kernel 1: Q/V projection, bf16 MFMA GEMM.  64x128 tiles, 4 waves (2x2),
// wave-tile 32x64.  M=4096, N=1536, K=768.  grid (12, 64), block 256.
// Epilogue: Q -> Qb bf16 [bh][s][64] + qn fp32 (from rounded q);
//           V -> Vt bf16 [bh][d][s].
// ---------------------------------------------------------------------------
__global__ __launch_bounds__(256) void qv_gemm(
    const unsigned short* __restrict__ hsb, const unsigned short* __restrict__ Wqvb,
    const float* __restrict__ bq, const float* __restrict__ bv,
    unsigned short* __restrict__ Qb, unsigned short* __restrict__ Vt,
    float* __restrict__ qn)
{
    __shared__ __align__(16) unsigned short As[64][40];
    __shared__ __align__(16) unsigned short Bs[128][40];

    const int t  = threadIdx.x;
    const int m0 = blockIdx.y << 6;
    const int c0 = blockIdx.x << 7;
    const bool isQ = (c0 < EDIM);
    const float* bias = isQ ? bq : bv;
    const int cb = isQ ? c0 : (c0 - EDIM);

    const int w  = t >> 6;
    const int l  = t & 63;
    const int ll = l & 15;
    const int lq = l >> 4;
    const int wx = w & 1;
    const int wy = w >> 1;

    const int srowA = t & 63;
    const int skA   = (t >> 6) << 3;   // 0,8,16,24
    const int srowB = t & 127;
    const int skB   = (t >> 7) << 4;   // 0,16

    f32x4 acc[2][4];
#pragma unroll
    for (int m = 0; m < 2; m++)
#pragma unroll
        for (int n = 0; n < 4; n++) acc[m][n] = (f32x4){0.f, 0.f, 0.f, 0.f};

    for (int k0 = 0; k0 < EDIM; k0 += 32) {
        bf16x8 va  = *(const bf16x8*)(hsb  + (size_t)(m0 + srowA) * EDIM + k0 + skA);
        bf16x8 vb0 = *(const bf16x8*)(Wqvb + (size_t)(c0 + srowB) * EDIM + k0 + skB);
        bf16x8 vb1 = *(const bf16x8*)(Wqvb + (size_t)(c0 + srowB) * EDIM + k0 + skB + 8);
        __syncthreads();
        *(bf16x8*)&As[srowA][skA]     = va;
        *(bf16x8*)&Bs[srowB][skB]     = vb0;
        *(bf16x8*)&Bs[srowB][skB + 8] = vb1;
        __syncthreads();
        bf16x8 aF[2], bF[4];
#pragma unroll
        for (int m = 0; m < 2; m++)
            aF[m] = *(const bf16x8*)&As[(wy << 5) + (m << 4) + ll][lq << 3];
#pragma unroll
        for (int n = 0; n < 4; n++)
            bF[n] = *(const bf16x8*)&Bs[(wx << 6) + (n << 4) + ll][lq << 3];
#pragma unroll
        for (int m = 0; m < 2; m++)
#pragma unroll
            for (int n = 0; n < 4; n++)
                acc[m][n] = __builtin_amdgcn_mfma_f32_16x16x32_bf16(aF[m], bF[n], acc[m][n], 0, 0, 0);
    }

    const int hcol0 = cb + (wx << 6);        // head-aligned
    const int h = hcol0 >> 6;
    const int rowbase = m0 + (wy << 5);
    const int b = rowbase >> 11;
    const int sbase = rowbase & 2047;

    if (isQ) {
#pragma unroll
        for (int m = 0; m < 2; m++) {
#pragma unroll
            for (int r = 0; r < 4; r++) {
                const int si = sbase + (m << 4) + (lq << 2) + r;
                unsigned short* qrow = Qb + ((size_t)(b * NH + h) * S_LEN + si) * HD;
                float qsq = 0.f;
#pragma unroll
                for (int n = 0; n < 4; n++) {
                    unsigned short u = f2bf(acc[m][n][r] + bias[hcol0 + (n << 4) + ll]);
                    qrow[(n << 4) + ll] = u;
                    float f = bf2f(u);
                    qsq += f * f;
                }
                qsq += __shfl_xor(qsq, 1);
                qsq += __shfl_xor(qsq, 2);
                qsq += __shfl_xor(qsq, 4);
                qsq += __shfl_xor(qsq, 8);
                if (ll == 0) qn[(b * NH + h) * S_LEN + si] = qsq;
            }
        }
    } else {
#pragma unroll
        for (int m = 0; m < 2; m++) {
            const int si = sbase + (m << 4) + (lq << 2);
#pragma unroll
            for (int n = 0; n < 4; n++) {
                ushort4 o;
                o.x = f2bf(acc[m][n][0] + bias[hcol0 + (n << 4) + ll]);
                o.y = f2bf(acc[m][n][1] + bias[hcol0 + (n << 4) + ll]);
                o.z = f2bf(acc[m][n][2] + bias[hcol0 + (n << 4) + ll]);
                o.w = f2bf(acc[m][n][3] + bias[hcol0 + (n << 4) + ll]);
                *(ushort4*)&Vt[((size_t)(b * NH + h) * HD + (n << 4) + ll) * S_LEN + si] = o;
            }
        }
    }
}

// ---------------------------------------------------------------------------
// Kernel 2: MFMA distance attention.  Single-wave blocks, 32 i-rows/wave
// (two 16-row MFMA sub-tiles sharing every B/V fragment -> half the cache
// traffic), pipelined: PV lags transform by one tile via double-buffered
// P strips.  Grid is LINEAR with id = ib*24 + bh: since 24 % 8 == 0, all
// blocks of one (b,h) land on the same XCD (id%8 == bh%8 under round-robin
// dispatch) -> per-XCD L2 working set = 3 heads * 512 KB = 1.5 MB < 4 MiB,
// so Q/V streams come from XCD-local L2, not Infinity Cache.
// grid (1536), block 64.
// ---------------------------------------------------------------------------
__global__ __launch_bounds__(64) void attn_kernel(
    const unsigned short* __restrict__ Qb, const unsigned short* __restrict__ Vt,
    const float* __restrict__ qn, const float* __restrict__ mask,
    unsigned short* __restrict__ AObf)
{
    __shared__ __align__(16) unsigned short Wt[2][2][16][40];  // [buf][sub][i][j+pad]

    const int l  = threadIdx.x;
    const int ll = l & 15;
    const int lq = l >> 4;
    const int id = blockIdx.x;
    const int ib = id / 24;
    const int bh = id - ib * 24;
    const int b  = bh / NH;
    const int h  = bh - b * NH;
    const int iw = ib << 5;                    // 32 i-rows

    const unsigned short* Qbase = Qb + ((size_t)bh << 17);
    const unsigned short* Vbase = Vt + ((size_t)bh << 17);
    const float* qnb = qn + (bh << 11);
    const float* mb  = mask + (b << 11);

    // A-frags for both 16-row sub-tiles, held all loop
    bf16x8 aQ[2][2];
#pragma unroll
    for (int s2 = 0; s2 < 2; s2++) {
        const unsigned short* qp = Qbase + (size_t)(iw + (s2 << 4) + ll) * HD + (lq << 3);
        aQ[s2][0] = *(const bf16x8*)qp;
        aQ[s2][1] = *(const bf16x8*)(qp + 32);
    }

    float qni[2][4], keepi[2][4];
#pragma unroll
    for (int s2 = 0; s2 < 2; s2++)
#pragma unroll
        for (int r = 0; r < 4; r++) {
            int row = iw + (s2 << 4) + (lq << 2) + r;
            qni[s2][r]   = qnb[row];
            keepi[s2][r] = (mb[row] >= 0.f) ? 1.f : 0.f;
        }

    bf16x8 ones;
#pragma unroll
    for (int i = 0; i < 8; i++) ones[i] = (short)0x3F80;   // bf16 1.0

    f32x4 oacc[2][4];
#pragma unroll
    for (int s2 = 0; s2 < 2; s2++)
#pragma unroll
        for (int m = 0; m < 4; m++) oacc[s2][m] = (f32x4){0.f, 0.f, 0.f, 0.f};
    f32x4 wacc[2];
    wacc[0] = (f32x4){0.f, 0.f, 0.f, 0.f};
    wacc[1] = (f32x4){0.f, 0.f, 0.f, 0.f};

    // gram B-frags for tile 0
    bf16x8 nb0[2], nb1[2];
#pragma unroll
    for (int n = 0; n < 2; n++) {
        const unsigned short* bp = Qbase + (size_t)((n << 4) + ll) * HD + (lq << 3);
        nb0[n] = *(const bf16x8*)bp;
        nb1[n] = *(const bf16x8*)(bp + 32);
    }
    bf16x8 vbuf[2][4];

    // ---- peeled iteration 0
    {
#pragma unroll
        for (int m = 0; m < 4; m++)
            vbuf[0][m] = *(const bf16x8*)(Vbase + (size_t)((m << 4) + ll) * S_LEN + (lq << 3));
        float qnjv[2], kjf[2];
#pragma unroll
        for (int n = 0; n < 2; n++) {
            int jc = (n << 4) + ll;
            qnjv[n] = qnb[jc];
            kjf[n]  = (mb[jc] >= 0.f) ? 1.f : 0.f;
        }
        f32x4 s[2][2];
#pragma unroll
        for (int s2 = 0; s2 < 2; s2++)
#pragma unroll
            for (int n = 0; n < 2; n++) {
                f32x4 c = (f32x4){0.f, 0.f, 0.f, 0.f};
                c = __builtin_amdgcn_mfma_f32_16x16x32_bf16(aQ[s2][0], nb0[n], c, 0, 0, 0);
                c = __builtin_amdgcn_mfma_f32_16x16x32_bf16(aQ[s2][1], nb1[n], c, 0, 0, 0);
                s[s2][n] = c;
            }
        // prefetch B-frags tile 1
#pragma unroll
        for (int n = 0; n < 2; n++) {
            const unsigned short* bp = Qbase + (size_t)(32 + (n << 4) + ll) * HD + (lq << 3);
            nb0[n] = *(const bf16x8*)bp;
            nb1[n] = *(const bf16x8*)(bp + 32);
        }
#pragma unroll
        for (int s2 = 0; s2 < 2; s2++)
#pragma unroll
            for (int n = 0; n < 2; n++)
#pragma unroll
                for (int r = 0; r < 4; r++) {
                    float d2   = fmaf(-2.f, s[s2][n][r], qni[s2][r] + qnjv[n]);
                    float dist = __builtin_amdgcn_sqrtf(fmaxf(d2, 1e-12f));
                    dist = (keepi[s2][r] * kjf[n] != 0.f) ? dist : 2.0f;
                    float x  = 1.0f + dist;
                    float x2 = x * x;
                    float x7 = x2 * x2 * x2 * x;
                    float p  = rsq_f32(x7);                   // (1+d)^-3.5
                    float wv = fmaf(fmaf(fmaf(fmaf(0.041666668f, p, 0.16666667f),
                                              p, 0.5f), p, 1.0f), p, 1.0f);
                    union { float f; unsigned int u; } cv; cv.f = wv;
                    Wt[0][s2][(lq << 2) + r][(n << 4) + ll] =
                        (unsigned short)((cv.u + 0x8000u) >> 16);
                }
    }

    for (int jt = 1; jt < 64; jt++) {
        const int j0 = jt << 5;
        const int jn = ((jt + 1) & 63) << 5;
        const int cur = jt & 1, prv = cur ^ 1;
        __builtin_amdgcn_wave_barrier();   // strip[prv] writes before reads below
        // V-frags for current tile (consumed next iteration)
#pragma unroll
        for (int m = 0; m < 4; m++)
            vbuf[cur][m] = *(const bf16x8*)(Vbase + (size_t)((m << 4) + ll) * S_LEN + j0 + (lq << 3));
        float qnjv[2], kjf[2];
#pragma unroll
        for (int n = 0; n < 2; n++) {
            int jc = j0 + (n << 4) + ll;
            qnjv[n] = qnb[jc];
            kjf[n]  = (mb[jc] >= 0.f) ? 1.f : 0.f;
        }
        // ---- gram(jt)
        f32x4 s[2][2];
#pragma unroll
        for (int s2 = 0; s2 < 2; s2++)
#pragma unroll
            for (int n = 0; n < 2; n++) {
                f32x4 c = (f32x4){0.f, 0.f, 0.f, 0.f};
                c = __builtin_amdgcn_mfma_f32_16x16x32_bf16(aQ[s2][0], nb0[n], c, 0, 0, 0);
                c = __builtin_amdgcn_mfma_f32_16x16x32_bf16(aQ[s2][1], nb1[n], c, 0, 0, 0);
                s[s2][n] = c;
            }
        // ---- prefetch B-frags(jt+1)
#pragma unroll
        for (int n = 0; n < 2; n++) {
            const unsigned short* bp = Qbase + (size_t)(jn + (n << 4) + ll) * HD + (lq << 3);
            nb0[n] = *(const bf16x8*)bp;
            nb1[n] = *(const bf16x8*)(bp + 32);
        }
        // ---- PV(jt-1)
#pragma unroll
        for (int s2 = 0; s2 < 2; s2++) {
            bf16x8 aP = *(const bf16x8*)&Wt[prv][s2][ll][lq << 3];
#pragma unroll
            for (int m = 0; m < 4; m++)
                oacc[s2][m] = __builtin_amdgcn_mfma_f32_16x16x32_bf16(aP, vbuf[prv][m], oacc[s2][m], 0, 0, 0);
            wacc[s2] = __builtin_amdgcn_mfma_f32_16x16x32_bf16(aP, ones, wacc[s2], 0, 0, 0);
        }
        // ---- transform(jt) -> strip[cur]
#pragma unroll
        for (int s2 = 0; s2 < 2; s2++)
#pragma unroll
            for (int n = 0; n < 2; n++)
#pragma unroll
                for (int r = 0; r < 4; r++) {
                    float d2   = fmaf(-2.f, s[s2][n][r], qni[s2][r] + qnjv[n]);
                    float dist = __builtin_amdgcn_sqrtf(fmaxf(d2, 1e-12f));
                    dist = (keepi[s2][r] * kjf[n] != 0.f) ? dist : 2.0f;
                    float x  = 1.0f + dist;
                    float x2 = x * x;
                    float x7 = x2 * x2 * x2 * x;
                    float p  = rsq_f32(x7);
                    float wv = fmaf(fmaf(fmaf(fmaf(0.041666668f, p, 0.16666667f),
                                              p, 0.5f), p, 1.0f), p, 1.0f);
                    union { float f; unsigned int u; } cv; cv.f = wv;
                    Wt[cur][s2][(lq << 2) + r][(n << 4) + ll] =
                        (unsigned short)((cv.u + 0x8000u) >> 16);
                }
    }

    // ---- drain: PV(63)
    __builtin_amdgcn_wave_barrier();
#pragma unroll
    for (int s2 = 0; s2 < 2; s2++) {
        bf16x8 aP = *(const bf16x8*)&Wt[1][s2][ll][lq << 3];
#pragma unroll
        for (int m = 0; m < 4; m++)
            oacc[s2][m] = __builtin_amdgcn_mfma_f32_16x16x32_bf16(aP, vbuf[1][m], oacc[s2][m], 0, 0, 0);
        wacc[s2] = __builtin_amdgcn_mfma_f32_16x16x32_bf16(aP, ones, wacc[s2], 0, 0, 0);
    }

#pragma unroll
    for (int s2 = 0; s2 < 2; s2++)
#pragma unroll
        for (int r = 0; r < 4; r++) {
            float inv = 1.0f / wacc[s2][r];
            const int row = iw + (s2 << 4) + (lq << 2) + r;
            unsigned short* dst = AObf + (size_t)((b << 11) + row) * EDIM + (h << 6);
#pragma unroll
            for (int m = 0; m < 4; m++)
                dst[(m << 4) + ll] = f2bf(oacc[s2][m][r] * inv);
        }
}

// ---------------------------------------------------------------------------
// Kernel 3a: out-projection bf16 MFMA GEMM + bias + residual (fp32 out).
// 64x64 tiles, 4 waves (2x2), wave-tile 32x32.  grid (12, 64), block 256.
// ---------------------------------------------------------------------------
__global__ __launch_bounds__(256) void oproj_gemm(
    const unsigned short* __restrict__ AObf, const unsigned short* __restrict__ Wob,
    const float* __restrict__ bo, const float* __restrict__ hs,
    float* __restrict__ TMP)
{
    __shared__ __align__(16) unsigned short As[64][40];
    __shared__ __align__(16) unsigned short Bs[64][40];

    const int t  = threadIdx.x;
    const int m0 = blockIdx.y << 6;
    const int c0 = blockIdx.x << 6;

    const int w  = t >> 6;
    const int l  = t & 63;
    const int ll = l & 15;
    const int lq = l >> 4;
    const int wx = w & 1;
    const int wy = w >> 1;

    const int srow = t & 63;
    const int sk   = (t >> 6) << 3;   // 0,8,16,24

    f32x4 acc[2][2];
#pragma unroll
    for (int m = 0; m < 2; m++)
#pragma unroll
        for (int n = 0; n < 2; n++) acc[m][n] = (f32x4){0.f, 0.f, 0.f, 0.f};

    for (int k0 = 0; k0 < EDIM; k0 += 32) {
        bf16x8 va = *(const bf16x8*)(AObf + (size_t)(m0 + srow) * EDIM + k0 + sk);
        bf16x8 vb = *(const bf16x8*)(Wob  + (size_t)(c0 + srow) * EDIM + k0 + sk);
        __syncthreads();
        *(bf16x8*)&As[srow][sk] = va;
        *(bf16x8*)&Bs[srow][sk] = vb;
        __syncthreads();
        bf16x8 aF[2], bF[2];
#pragma unroll
        for (int m = 0; m < 2; m++)
            aF[m] = *(const bf16x8*)&As[(wy << 5) + (m << 4) + ll][lq << 3];
#pragma unroll
        for (int n = 0; n < 2; n++)
            bF[n] = *(const bf16x8*)&Bs[(wx << 5) + (n << 4) + ll][lq << 3];
#pragma unroll
        for (int m = 0; m < 2; m++)
#pragma unroll
            for (int n = 0; n < 2; n++)
                acc[m][n] = __builtin_amdgcn_mfma_f32_16x16x32_bf16(aF[m], bF[n], acc[m][n], 0, 0, 0);
    }

#pragma unroll
    for (int m = 0; m < 2; m++) {
#pragma unroll
        for (int r = 0; r < 4; r++) {
            const int row = m0 + (wy << 5) + (m << 4) + (lq << 2) + r;
#pragma unroll
            for (int n = 0; n < 2; n++) {
                const int col = c0 + (wx << 5) + (n << 4) + ll;
                TMP[(size_t)row * EDIM + col] =
                    acc[m][n][r] + bo[col] + hs[(size_t)row * EDIM + col];
            }
        }
    }
}

// ---------------------------------------------------------------------------
// Kernel 3b: LayerNorm -> f32 output.  grid 4096, block 256.
// ---------------------------------------------------------------------------
__global__ __launch_bounds__(256) void ln_kernel(
    const float* __restrict__ X, const float* __restrict__ g,
    const float* __restrict__ be, float* __restrict__ out)
{
    const int row = blockIdx.x;
    const int t = threadIdx.x;
    const float* x = X + (size_t)row * EDIM;

    float s = 0.f, sq = 0.f;
#pragma unroll
    for (int c = t; c < EDIM; c += 256) {
        float v = x[c];
        s += v; sq += v * v;
    }
#pragma unroll
    for (int m = 1; m < 64; m <<= 1) {
        s  += __shfl_xor(s, m);
        sq += __shfl_xor(sq, m);
    }
    __shared__ float ss[4], ssq[4];
    const int w = t >> 6;
    if ((t & 63) == 0) { ss[w] = s; ssq[w] = sq; }
    __syncthreads();
    s  = ss[0] + ss[1] + ss[2] + ss[3];
    sq = ssq[0] + ssq[1] + ssq[2] + ssq[3];
    const float mu  = s * (1.f / EDIM);
    const float var = sq * (1.f / EDIM) - mu * mu;
    const float rstd = 1.0f / sqrtf(var + 1e-12f);

#pragma unroll
    for (int c = t; c < EDIM; c += 256) {
        out[(size_t)row * EDIM + c] = (x[c] - mu) * rstd * g[c] + be[c];
    }
}

// ---------------------------------------------------------------------------
extern "C" void kernel_launch(void* const* d_in, const int* in_sizes, int n_in,
                              void* d_out, int out_size, void* d_ws, size_t ws_size,
                              hipStream_t stream) {
    const float* hs   = (const float*)d_in[0];
    const float* mask = (const float*)d_in[1];
    const float* Wq   = (const float*)d_in[2];
    const float* bq   = (const float*)d_in[3];
    const float* Wv   = (const float*)d_in[4];
    const float* bv   = (const float*)d_in[5];
    const float* Wo   = (const float*)d_in[6];
    const float* bo   = (const float*)d_in[7];
    const float* g    = (const float*)d_in[8];
    const float* be   = (const float*)d_in[9];

    char* w8 = (char*)d_ws;
    unsigned short* Qb   = (unsigned short*)(w8);               //  6,291,456 B
    unsigned short* Vt   = (unsigned short*)(w8 +  6291456);    //  6,291,456 B
    float*          qn   = (float*)        (w8 + 12582912);     //    196,608 B
    unsigned short* AObf = (unsigned short*)(w8 + 12779520);    //  6,291,456 B
    unsigned short* hsb  = (unsigned short*)(w8 + 19070976);    //  6,291,456 B
    unsigned short* Wqvb = (unsigned short*)(w8 + 25362432);    //  2,359,296 B
    unsigned short* Wob  = (unsigned short*)(w8 + 27721728);    //  1,179,648 B
    float*          TMP  = (float*)(w8);                        // alias Qb+Vt (dead)

    precast_kernel<<<dim3(4800),    256, 0, stream>>>(hs, Wq, Wv, Wo, hsb, Wqvb, Wob);
    qv_gemm       <<<dim3(12, 64),  256, 0, stream>>>(hsb, Wqvb, bq, bv, Qb, Vt, qn);
    attn_kernel   <<<dim3(1536),    64,  0, stream>>>(Qb, Vt, qn, mask, AObf);
    oproj_gemm    <<<dim3(12, 64),  256, 0, stream>>>(AObf, Wob, bo, hs, TMP);
    ln_kernel     <<<dim3(4096),    256, 0, stream>>>(TMP, g, be, (float*)d_out);
}

// Round 10
// 261.335 us; speedup vs baseline: 12.1174x; 12.1174x over previous
//
#include <hip/hip_runtime.h>
#include <hip/hip_bf16.h>
#include <cstdint>
#include <cstddef>

#define S_LEN 2048
#define NH 12
#define HD 64
#define EDIM 768
// exponent = -(D_INTRINSIC + BETA) = -3.5, BANDWIDTH^0.5 = 1

typedef short bf16x8 __attribute__((ext_vector_type(8)));
typedef float f32x4  __attribute__((ext_vector_type(4)));

__device__ __forceinline__ unsigned short f2bf(float f) {
    return __bfloat16_as_ushort(__float2bfloat16(f));
}
__device__ __forceinline__ float bf2f(unsigned short u) {
    union { unsigned int i; float f; } x;
    x.i = ((unsigned int)u) << 16;
    return x.f;
}
__device__ __forceinline__ float rsq_f32(float x) {
#if __has_builtin(__builtin_amdgcn_rsqf)
    return __builtin_amdgcn_rsqf(x);
#else
    return __builtin_amdgcn_rcpf(__builtin_amdgcn_sqrtf(x));
#endif
}

// ---------------------------------------------------------------------------
// Kernel 0: one-shot fp32 -> bf16 pre-cast of hs, Wq|Wv (concatenated), Wo.
// ---------------------------------------------------------------------------
__global__ __launch_bounds__(256) void precast_kernel(
    const float* __restrict__ hs, const float* __restrict__ Wq,
    const float* __restrict__ Wv, const float* __restrict__ Wo,
    unsigned short* __restrict__ hsb, unsigned short* __restrict__ Wqvb,
    unsigned short* __restrict__ Wob)
{
    const int i4 = blockIdx.x * 256 + threadIdx.x;   // 0..1228799
    const float* src;
    unsigned short* dst;
    int rel;
    if (i4 < 786432)        { src = hs; dst = hsb;            rel = i4; }
    else if (i4 < 933888)   { src = Wq; dst = Wqvb;           rel = i4 - 786432; }
    else if (i4 < 1081344)  { src = Wv; dst = Wqvb + 589824;  rel = i4 - 933888; }
    else                    { src = Wo; dst = Wob;            rel = i4 - 1081344; }
    float4 v = ((const float4*)src)[rel];
    ushort4 o;
    o.x = f2bf(v.x); o.y = f2bf(v.y); o.z = f2bf(v.z); o.w = f2bf(v.w);
    ((ushort4*)dst)[rel] = o;
}

// ---------------------------------------------------------------------------
// Kernel 1: Q/V projection, bf16 MFMA GEMM.  64x128 tiles, 4 waves (2x2),
// wave-tile 32x64.  M=4096, N=1536, K=768.  grid (12, 64), block 256.
// Epilogue: Q -> Qb bf16 [bh][s][64] + qn fp32 (from rounded q);
//           V -> Vt bf16 [bh][d][s].
// ---------------------------------------------------------------------------
__global__ __launch_bounds__(256) void qv_gemm(
    const unsigned short* __restrict__ hsb, const unsigned short* __restrict__ Wqvb,
    const float* __restrict__ bq, const float* __restrict__ bv,
    unsigned short* __restrict__ Qb, unsigned short* __restrict__ Vt,
    float* __restrict__ qn)
{
    __shared__ __align__(16) unsigned short As[64][40];
    __shared__ __align__(16) unsigned short Bs[128][40];

    const int t  = threadIdx.x;
    const int m0 = blockIdx.y << 6;
    const int c0 = blockIdx.x << 7;
    const bool isQ = (c0 < EDIM);
    const float* bias = isQ ? bq : bv;
    const int cb = isQ ? c0 : (c0 - EDIM);

    const int w  = t >> 6;
    const int l  = t & 63;
    const int ll = l & 15;
    const int lq = l >> 4;
    const int wx = w & 1;
    const int wy = w >> 1;

    const int srowA = t & 63;
    const int skA   = (t >> 6) << 3;   // 0,8,16,24
    const int srowB = t & 127;
    const int skB   = (t >> 7) << 4;   // 0,16

    f32x4 acc[2][4];
#pragma unroll
    for (int m = 0; m < 2; m++)
#pragma unroll
        for (int n = 0; n < 4; n++) acc[m][n] = (f32x4){0.f, 0.f, 0.f, 0.f};

    for (int k0 = 0; k0 < EDIM; k0 += 32) {
        bf16x8 va  = *(const bf16x8*)(hsb  + (size_t)(m0 + srowA) * EDIM + k0 + skA);
        bf16x8 vb0 = *(const bf16x8*)(Wqvb + (size_t)(c0 + srowB) * EDIM + k0 + skB);
        bf16x8 vb1 = *(const bf16x8*)(Wqvb + (size_t)(c0 + srowB) * EDIM + k0 + skB + 8);
        __syncthreads();
        *(bf16x8*)&As[srowA][skA]     = va;
        *(bf16x8*)&Bs[srowB][skB]     = vb0;
        *(bf16x8*)&Bs[srowB][skB + 8] = vb1;
        __syncthreads();
        bf16x8 aF[2], bF[4];
#pragma unroll
        for (int m = 0; m < 2; m++)
            aF[m] = *(const bf16x8*)&As[(wy << 5) + (m << 4) + ll][lq << 3];
#pragma unroll
        for (int n = 0; n < 4; n++)
            bF[n] = *(const bf16x8*)&Bs[(wx << 6) + (n << 4) + ll][lq << 3];
#pragma unroll
        for (int m = 0; m < 2; m++)
#pragma unroll
            for (int n = 0; n < 4; n++)
                acc[m][n] = __builtin_amdgcn_mfma_f32_16x16x32_bf16(aF[m], bF[n], acc[m][n], 0, 0, 0);
    }

    const int hcol0 = cb + (wx << 6);        // head-aligned
    const int h = hcol0 >> 6;
    const int rowbase = m0 + (wy << 5);
    const int b = rowbase >> 11;
    const int sbase = rowbase & 2047;

    if (isQ) {
#pragma unroll
        for (int m = 0; m < 2; m++) {
#pragma unroll
            for (int r = 0; r < 4; r++) {
                const int si = sbase + (m << 4) + (lq << 2) + r;
                unsigned short* qrow = Qb + ((size_t)(b * NH + h) * S_LEN + si) * HD;
                float qsq = 0.f;
#pragma unroll
                for (int n = 0; n < 4; n++) {
                    unsigned short u = f2bf(acc[m][n][r] + bias[hcol0 + (n << 4) + ll]);
                    qrow[(n << 4) + ll] = u;
                    float f = bf2f(u);
                    qsq += f * f;
                }
                qsq += __shfl_xor(qsq, 1);
                qsq += __shfl_xor(qsq, 2);
                qsq += __shfl_xor(qsq, 4);
                qsq += __shfl_xor(qsq, 8);
                if (ll == 0) qn[(b * NH + h) * S_LEN + si] = qsq;
            }
        }
    } else {
#pragma unroll
        for (int m = 0; m < 2; m++) {
            const int si = sbase + (m << 4) + (lq << 2);
#pragma unroll
            for (int n = 0; n < 4; n++) {
                ushort4 o;
                o.x = f2bf(acc[m][n][0] + bias[hcol0 + (n << 4) + ll]);
                o.y = f2bf(acc[m][n][1] + bias[hcol0 + (n << 4) + ll]);
                o.z = f2bf(acc[m][n][2] + bias[hcol0 + (n << 4) + ll]);
                o.w = f2bf(acc[m][n][3] + bias[hcol0 + (n << 4) + ll]);
                *(ushort4*)&Vt[((size_t)(b * NH + h) * HD + (n << 4) + ll) * S_LEN + si] = o;
            }
        }
    }
}

// ---------------------------------------------------------------------------
// attn tile step, CUR is a template constant so vbuf/Wt indexing is
// compile-time (register-resident) WITHOUT any unroll pragma.
// ---------------------------------------------------------------------------
template<int CUR>
__device__ __forceinline__ void attn_tile(
    int j0, int jn,
    const unsigned short* __restrict__ Qbase,
    const unsigned short* __restrict__ Vbase,
    const float* __restrict__ qnb, const float* __restrict__ mb,
    int ll, int lq,
    const bf16x8 (&aQ)[2][2],
    const float (&qni)[2][4], const float (&keepi)[2][4],
    const bf16x8& ones,
    f32x4 (&oacc)[2][4], f32x4 (&wacc)[2],
    bf16x8 (&nb0)[2], bf16x8 (&nb1)[2],
    bf16x8 (&vbuf)[2][4],
    unsigned short (&Wt)[2][2][16][40])
{
    constexpr int PRV = CUR ^ 1;
    __builtin_amdgcn_wave_barrier();   // strip[PRV] writes (prev tile) before reads below
    // V-frags for current tile (consumed next tile)
#pragma unroll
    for (int m = 0; m < 4; m++)
        vbuf[CUR][m] = *(const bf16x8*)(Vbase + (size_t)((m << 4) + ll) * S_LEN + j0 + (lq << 3));
    float qnjv[2], kjf[2];
#pragma unroll
    for (int n = 0; n < 2; n++) {
        int jc = j0 + (n << 4) + ll;
        qnjv[n] = qnb[jc];
        kjf[n]  = (mb[jc] >= 0.f) ? 1.f : 0.f;
    }
    // ---- gram(j0) with prefetched B-frags
    f32x4 s[2][2];
#pragma unroll
    for (int s2 = 0; s2 < 2; s2++)
#pragma unroll
        for (int n = 0; n < 2; n++) {
            f32x4 c = (f32x4){0.f, 0.f, 0.f, 0.f};
            c = __builtin_amdgcn_mfma_f32_16x16x32_bf16(aQ[s2][0], nb0[n], c, 0, 0, 0);
            c = __builtin_amdgcn_mfma_f32_16x16x32_bf16(aQ[s2][1], nb1[n], c, 0, 0, 0);
            s[s2][n] = c;
        }
    // ---- prefetch B-frags(next tile)
#pragma unroll
    for (int n = 0; n < 2; n++) {
        const unsigned short* bp = Qbase + (size_t)(jn + (n << 4) + ll) * HD + (lq << 3);
        nb0[n] = *(const bf16x8*)bp;
        nb1[n] = *(const bf16x8*)(bp + 32);
    }
    // ---- PV(previous tile)
#pragma unroll
    for (int s2 = 0; s2 < 2; s2++) {
        bf16x8 aP = *(const bf16x8*)&Wt[PRV][s2][ll][lq << 3];
#pragma unroll
        for (int m = 0; m < 4; m++)
            oacc[s2][m] = __builtin_amdgcn_mfma_f32_16x16x32_bf16(aP, vbuf[PRV][m], oacc[s2][m], 0, 0, 0);
        wacc[s2] = __builtin_amdgcn_mfma_f32_16x16x32_bf16(aP, ones, wacc[s2], 0, 0, 0);
    }
    // ---- transform(current) -> strip[CUR]
#pragma unroll
    for (int s2 = 0; s2 < 2; s2++)
#pragma unroll
        for (int n = 0; n < 2; n++)
#pragma unroll
            for (int r = 0; r < 4; r++) {
                float d2   = fmaf(-2.f, s[s2][n][r], qni[s2][r] + qnjv[n]);
                float dist = __builtin_amdgcn_sqrtf(fmaxf(d2, 1e-12f));
                dist = (keepi[s2][r] * kjf[n] != 0.f) ? dist : 2.0f;
                float x  = 1.0f + dist;
                float x2 = x * x;
                float x7 = x2 * x2 * x2 * x;
                float p  = rsq_f32(x7);                       // (1+d)^-3.5
                float wv = fmaf(fmaf(fmaf(fmaf(0.041666668f, p, 0.16666667f),
                                          p, 0.5f), p, 1.0f), p, 1.0f);
                union { float f; unsigned int u; } cv; cv.f = wv;
                Wt[CUR][s2][(lq << 2) + r][(n << 4) + ll] =
                    (unsigned short)((cv.u + 0x8000u) >> 16);
            }
}

// ---------------------------------------------------------------------------
// Kernel 2: MFMA distance attention.  Single-wave blocks, 32 i-rows/wave
// (two 16-row MFMA sub-tiles sharing every B/V fragment -> half the cache
// traffic), pipelined: PV lags transform by one tile via double-buffered
// P strips (template-unrolled tile pairs; no unroll pragma needed).
// Grid LINEAR, id = ib*24 + bh: 24 % 8 == 0, so all blocks of one (b,h)
// land on the same XCD under round-robin dispatch -> per-XCD L2 working
// set 1.5 MB < 4 MiB.  grid (1536), block 64.
// ---------------------------------------------------------------------------
__global__ __launch_bounds__(64) void attn_kernel(
    const unsigned short* __restrict__ Qb, const unsigned short* __restrict__ Vt,
    const float* __restrict__ qn, const float* __restrict__ mask,
    unsigned short* __restrict__ AObf)
{
    __shared__ __align__(16) unsigned short Wt[2][2][16][40];  // [buf][sub][i][j+pad]

    const int l  = threadIdx.x;
    const int ll = l & 15;
    const int lq = l >> 4;
    const int id = blockIdx.x;
    const int ib = id / 24;
    const int bh = id - ib * 24;
    const int b  = bh / NH;
    const int h  = bh - b * NH;
    const int iw = ib << 5;                    // 32 i-rows

    const unsigned short* Qbase = Qb + ((size_t)bh << 17);
    const unsigned short* Vbase = Vt + ((size_t)bh << 17);
    const float* qnb = qn + (bh << 11);
    const float* mb  = mask + (b << 11);

    // A-frags for both 16-row sub-tiles, held all loop
    bf16x8 aQ[2][2];
#pragma unroll
    for (int s2 = 0; s2 < 2; s2++) {
        const unsigned short* qp = Qbase + (size_t)(iw + (s2 << 4) + ll) * HD + (lq << 3);
        aQ[s2][0] = *(const bf16x8*)qp;
        aQ[s2][1] = *(const bf16x8*)(qp + 32);
    }

    float qni[2][4], keepi[2][4];
#pragma unroll
    for (int s2 = 0; s2 < 2; s2++)
#pragma unroll
        for (int r = 0; r < 4; r++) {
            int row = iw + (s2 << 4) + (lq << 2) + r;
            qni[s2][r]   = qnb[row];
            keepi[s2][r] = (mb[row] >= 0.f) ? 1.f : 0.f;
        }

    bf16x8 ones;
#pragma unroll
    for (int i = 0; i < 8; i++) ones[i] = (short)0x3F80;   // bf16 1.0

    f32x4 oacc[2][4];
#pragma unroll
    for (int s2 = 0; s2 < 2; s2++)
#pragma unroll
        for (int m = 0; m < 4; m++) oacc[s2][m] = (f32x4){0.f, 0.f, 0.f, 0.f};
    f32x4 wacc[2];
    wacc[0] = (f32x4){0.f, 0.f, 0.f, 0.f};
    wacc[1] = (f32x4){0.f, 0.f, 0.f, 0.f};

    // gram B-frags for tile 0
    bf16x8 nb0[2], nb1[2];
#pragma unroll
    for (int n = 0; n < 2; n++) {
        const unsigned short* bp = Qbase + (size_t)((n << 4) + ll) * HD + (lq << 3);
        nb0[n] = *(const bf16x8*)bp;
        nb1[n] = *(const bf16x8*)(bp + 32);
    }
    bf16x8 vbuf[2][4];

    // ---- peeled tile 0: V(0) -> vbuf[0], scores(0) -> strip[0],
    //      prefetch B-frags for tile 1
    {
#pragma unroll
        for (int m = 0; m < 4; m++)
            vbuf[0][m] = *(const bf16x8*)(Vbase + (size_t)((m << 4) + ll) * S_LEN + (lq << 3));
        float qnjv[2], kjf[2];
#pragma unroll
        for (int n = 0; n < 2; n++) {
            int jc = (n << 4) + ll;
            qnjv[n] = qnb[jc];
            kjf[n]  = (mb[jc] >= 0.f) ? 1.f : 0.f;
        }
        f32x4 s[2][2];
#pragma unroll
        for (int s2 = 0; s2 < 2; s2++)
#pragma unroll
            for (int n = 0; n < 2; n++) {
                f32x4 c = (f32x4){0.f, 0.f, 0.f, 0.f};
                c = __builtin_amdgcn_mfma_f32_16x16x32_bf16(aQ[s2][0], nb0[n], c, 0, 0, 0);
                c = __builtin_amdgcn_mfma_f32_16x16x32_bf16(aQ[s2][1], nb1[n], c, 0, 0, 0);
                s[s2][n] = c;
            }
#pragma unroll
        for (int n = 0; n < 2; n++) {
            const unsigned short* bp = Qbase + (size_t)(32 + (n << 4) + ll) * HD + (lq << 3);
            nb0[n] = *(const bf16x8*)bp;
            nb1[n] = *(const bf16x8*)(bp + 32);
        }
#pragma unroll
        for (int s2 = 0; s2 < 2; s2++)
#pragma unroll
            for (int n = 0; n < 2; n++)
#pragma unroll
                for (int r = 0; r < 4; r++) {
                    float d2   = fmaf(-2.f, s[s2][n][r], qni[s2][r] + qnjv[n]);
                    float dist = __builtin_amdgcn_sqrtf(fmaxf(d2, 1e-12f));
                    dist = (keepi[s2][r] * kjf[n] != 0.f) ? dist : 2.0f;
                    float x  = 1.0f + dist;
                    float x2 = x * x;
                    float x7 = x2 * x2 * x2 * x;
                    float p  = rsq_f32(x7);
                    float wv = fmaf(fmaf(fmaf(fmaf(0.041666668f, p, 0.16666667f),
                                              p, 0.5f), p, 1.0f), p, 1.0f);
                    union { float f; unsigned int u; } cv; cv.f = wv;
                    Wt[0][s2][(lq << 2) + r][(n << 4) + ll] =
                        (unsigned short)((cv.u + 0x8000u) >> 16);
                }
    }

    // ---- tiles 1..62 as 31 template-unrolled pairs (odd tile CUR=1,
    //      even tile CUR=0)
    for (int base = 1; base <= 61; base += 2) {
        attn_tile<1>(base << 5, (base + 1) << 5, Qbase, Vbase, qnb, mb, ll, lq,
                     aQ, qni, keepi, ones, oacc, wacc, nb0, nb1, vbuf, Wt);
        attn_tile<0>((base + 1) << 5, (base + 2) << 5, Qbase, Vbase, qnb, mb, ll, lq,
                     aQ, qni, keepi, ones, oacc, wacc, nb0, nb1, vbuf, Wt);
    }
    // ---- tile 63 (CUR=1; next-prefetch wraps to 0, harmless)
    attn_tile<1>(63 << 5, 0, Qbase, Vbase, qnb, mb, ll, lq,
                 aQ, qni, keepi, ones, oacc, wacc, nb0, nb1, vbuf, Wt);

    // ---- drain: PV(63) from strip[1]/vbuf[1]
    __builtin_amdgcn_wave_barrier();
#pragma unroll
    for (int s2 = 0; s2 < 2; s2++) {
        bf16x8 aP = *(const bf16x8*)&Wt[1][s2][ll][lq << 3];
#pragma unroll
        for (int m = 0; m < 4; m++)
            oacc[s2][m] = __builtin_amdgcn_mfma_f32_16x16x32_bf16(aP, vbuf[1][m], oacc[s2][m], 0, 0, 0);
        wacc[s2] = __builtin_amdgcn_mfma_f32_16x16x32_bf16(aP, ones, wacc[s2], 0, 0, 0);
    }

#pragma unroll
    for (int s2 = 0; s2 < 2; s2++)
#pragma unroll
        for (int r = 0; r < 4; r++) {
            float inv = 1.0f / wacc[s2][r];
            const int row = iw + (s2 << 4) + (lq << 2) + r;
            unsigned short* dst = AObf + (size_t)((b << 11) + row) * EDIM + (h << 6);
#pragma unroll
            for (int m = 0; m < 4; m++)
                dst[(m << 4) + ll] = f2bf(oacc[s2][m][r] * inv);
        }
}

// ---------------------------------------------------------------------------
// Kernel 3a: out-projection bf16 MFMA GEMM + bias + residual (fp32 out).
// 64x64 tiles, 4 waves (2x2), wave-tile 32x32.  grid (12, 64), block 256.
// ---------------------------------------------------------------------------
__global__ __launch_bounds__(256) void oproj_gemm(
    const unsigned short* __restrict__ AObf, const unsigned short* __restrict__ Wob,
    const float* __restrict__ bo, const float* __restrict__ hs,
    float* __restrict__ TMP)
{
    __shared__ __align__(16) unsigned short As[64][40];
    __shared__ __align__(16) unsigned short Bs[64][40];

    const int t  = threadIdx.x;
    const int m0 = blockIdx.y << 6;
    const int c0 = blockIdx.x << 6;

    const int w  = t >> 6;
    const int l  = t & 63;
    const int ll = l & 15;
    const int lq = l >> 4;
    const int wx = w & 1;
    const int wy = w >> 1;

    const int srow = t & 63;
    const int sk   = (t >> 6) << 3;   // 0,8,16,24

    f32x4 acc[2][2];
#pragma unroll
    for (int m = 0; m < 2; m++)
#pragma unroll
        for (int n = 0; n < 2; n++) acc[m][n] = (f32x4){0.f, 0.f, 0.f, 0.f};

    for (int k0 = 0; k0 < EDIM; k0 += 32) {
        bf16x8 va = *(const bf16x8*)(AObf + (size_t)(m0 + srow) * EDIM + k0 + sk);
        bf16x8 vb = *(const bf16x8*)(Wob  + (size_t)(c0 + srow) * EDIM + k0 + sk);
        __syncthreads();
        *(bf16x8*)&As[srow][sk] = va;
        *(bf16x8*)&Bs[srow][sk] = vb;
        __syncthreads();
        bf16x8 aF[2], bF[2];
#pragma unroll
        for (int m = 0; m < 2; m++)
            aF[m] = *(const bf16x8*)&As[(wy << 5) + (m << 4) + ll][lq << 3];
#pragma unroll
        for (int n = 0; n < 2; n++)
            bF[n] = *(const bf16x8*)&Bs[(wx << 5) + (n << 4) + ll][lq << 3];
#pragma unroll
        for (int m = 0; m < 2; m++)
#pragma unroll
            for (int n = 0; n < 2; n++)
                acc[m][n] = __builtin_amdgcn_mfma_f32_16x16x32_bf16(aF[m], bF[n], acc[m][n], 0, 0, 0);
    }

#pragma unroll
    for (int m = 0; m < 2; m++) {
#pragma unroll
        for (int r = 0; r < 4; r++) {
            const int row = m0 + (wy << 5) + (m << 4) + (lq << 2) + r;
#pragma unroll
            for (int n = 0; n < 2; n++) {
                const int col = c0 + (wx << 5) + (n << 4) + ll;
                TMP[(size_t)row * EDIM + col] =
                    acc[m][n][r] + bo[col] + hs[(size_t)row * EDIM + col];
            }
        }
    }
}

// ---------------------------------------------------------------------------
// Kernel 3b: LayerNorm -> f32 output.  grid 4096, block 256.
// ---------------------------------------------------------------------------
__global__ __launch_bounds__(256) void ln_kernel(
    const float* __restrict__ X, const float* __restrict__ g,
    const float* __restrict__ be, float* __restrict__ out)
{
    const int row = blockIdx.x;
    const int t = threadIdx.x;
    const float* x = X + (size_t)row * EDIM;

    float s = 0.f, sq = 0.f;
#pragma unroll
    for (int c = t; c < EDIM; c += 256) {
        float v = x[c];
        s += v; sq += v * v;
    }
#pragma unroll
    for (int m = 1; m < 64; m <<= 1) {
        s  += __shfl_xor(s, m);
        sq += __shfl_xor(sq, m);
    }
    __shared__ float ss[4], ssq[4];
    const int w = t >> 6;
    if ((t & 63) == 0) { ss[w] = s; ssq[w] = sq; }
    __syncthreads();
    s  = ss[0] + ss[1] + ss[2] + ss[3];
    sq = ssq[0] + ssq[1] + ssq[2] + ssq[3];
    const float mu  = s * (1.f / EDIM);
    const float var = sq * (1.f / EDIM) - mu * mu;
    const float rstd = 1.0f / sqrtf(var + 1e-12f);

#pragma unroll
    for (int c = t; c < EDIM; c += 256) {
        out[(size_t)row * EDIM + c] = (x[c] - mu) * rstd * g[c] + be[c];
    }
}

// ---------------------------------------------------------------------------
extern "C" void kernel_launch(void* const* d_in, const int* in_sizes, int n_in,
                              void* d_out, int out_size, void* d_ws, size_t ws_size,
                              hipStream_t stream) {
    const float* hs   = (const float*)d_in[0];
    const float* mask = (const float*)d_in[1];
    const float* Wq   = (const float*)d_in[2];
    const float* bq   = (const float*)d_in[3];
    const float* Wv   = (const float*)d_in[4];
    const float* bv   = (const float*)d_in[5];
    const float* Wo   = (const float*)d_in[6];
    const float* bo   = (const float*)d_in[7];
    const float* g    = (const float*)d_in[8];
    const float* be   = (const float*)d_in[9];

    char* w8 = (char*)d_ws;
    unsigned short* Qb   = (unsigned short*)(w8);               //  6,291,456 B
    unsigned short* Vt   = (unsigned short*)(w8 +  6291456);    //  6,291,456 B
    float*          qn   = (float*)        (w8 + 12582912);     //    196,608 B
    unsigned short* AObf = (unsigned short*)(w8 + 12779520);    //  6,291,456 B
    unsigned short* hsb  = (unsigned short*)(w8 + 19070976);    //  6,291,456 B
    unsigned short* Wqvb = (unsigned short*)(w8 + 25362432);    //  2,359,296 B
    unsigned short* Wob  = (unsigned short*)(w8 + 27721728);    //  1,179,648 B
    float*          TMP  = (float*)(w8);                        // alias Qb+Vt (dead)

    precast_kernel<<<dim3(4800),    256, 0, stream>>>(hs, Wq, Wv, Wo, hsb, Wqvb, Wob);
    qv_gemm       <<<dim3(12, 64),  256, 0, stream>>>(hsb, Wqvb, bq, bv, Qb, Vt, qn);
    attn_kernel   <<<dim3(1536),    64,  0, stream>>>(Qb, Vt, qn, mask, AObf);
    oproj_gemm    <<<dim3(12, 64),  256, 0, stream>>>(AObf, Wob, bo, hs, TMP);
    ln_kernel     <<<dim3(4096),    256, 0, stream>>>(TMP, g, be, (float*)d_out);
}